// Round 4
// baseline (373.886 us; speedup 1.0000x reference)
//
#include <hip/hip_runtime.h>
#include <stdint.h>

// ---------------------------------------------------------------------------
// OptitationLayer: sliding-window attention (W=9) with projections.
//   S=32768, D=1024, R=256. Inputs/outputs FLOAT32; bf16 MFMA internally.
// Pipeline (4 kernels):
//   prep_all: weight transposes f32->bf16 (blocks 0..1024) OVERLAPPED with
//             x f32->bf16 convert (blocks 1025..3072)
//   gemm_dp : QKV[S][768] bf16 = x_bf16 @ W + bias
//   attn    : QKV[i][0:256] <- softmax-window ctx (in-place, 4 queries/wave)
//   gemm_dp : out[S][1024] f32 = ctx @ Wo + bo
//
// gemm_dp schedule (deep-pipeline, sync amortized 2x vs 128^2 structure):
//   BM=256, BN=128, BK=64, 512 threads (8 waves as 4Mx2N, per-wave 64x64).
//   Ring-of-3 K-tile LDS buffers: 3 x (A 32KB + B 16KB) = 144 KB -> 1 blk/CU.
//   Per K-tile t: ONE fused gate {s_waitcnt vmcnt(6); s_barrier}, then stage
//   tile t+2 (6 async16/thread), 16 ds_read_b128, 32 MFMA. Staging is 2 tiles
//   ahead -> in-flight window ~2 bodies (~700cy) covers HBM latency; vmcnt(6)
//   never drains fresh loads (steady state: 12 outstanding -> keep newest 6).
//   Race safety: buf[(t+2)%3] == buf[(t-1)%3]; its last readers (tile t-1's
//   ds_reads) all precede gate-t's barrier; reads of buf[t%3] are gated by
//   each wave's vmcnt(6) + common barrier (single asm -> no reordering).
//   Grid: gemm1 = 128x6 = 768 blocks @1/CU = exactly 3 dispatch rounds (no
//   tail); gemm2 = 128x8 = 1024 = 4 rounds. XCD swizzle: all n-tiles of an
//   m-row on one XCD (A panel fetched by a single L2).
//   LDS swizzle (BK=64: 8x 16B chunks/row): phys = c ^ (row&7), applied on
//   pre-swizzled global source AND ds_read side; worst 2-way aliasing (free).
//   Accumulation order over k identical to previous rounds -> bit-identical.
// ---------------------------------------------------------------------------

typedef __attribute__((ext_vector_type(8))) short short8;   // 8 x bf16 frag
typedef __attribute__((ext_vector_type(4))) float floatx4;  // MFMA acc

typedef __attribute__((address_space(1))) const void global_cv;
typedef __attribute__((address_space(3))) void lds_v;

__device__ __forceinline__ float b2f(unsigned short u) {
  union { float f; uint32_t i; } v; v.i = ((uint32_t)u) << 16; return v.f;
}
__device__ __forceinline__ unsigned short f2b(float f) {
  union { float f; uint32_t i; } v; v.f = f;
  uint32_t x = v.i;
  return (unsigned short)((x + 0x7FFFu + ((x >> 16) & 1u)) >> 16);
}
// pack two f32 -> two bf16 (round half-up; 3 VALU ops)
__device__ __forceinline__ uint32_t pack2bf(float a, float b) {
  uint32_t ua = (__float_as_uint(a) + 0x8000u) >> 16;
  uint32_t ub = (__float_as_uint(b) + 0x8000u) & 0xFFFF0000u;
  return ua | ub;
}

// async 16B global->LDS; lane i lands at lds_base + i*16 (wave-uniform base)
__device__ __forceinline__ void async16(const unsigned short* g, unsigned short* s) {
  __builtin_amdgcn_global_load_lds((global_cv*)g, (lds_v*)s, 16, 0, 0);
}

__device__ __forceinline__ void storeC(unsigned short* C, size_t idx, float v) {
  C[idx] = f2b(v);
}
__device__ __forceinline__ void storeC(float* C, size_t idx, float v) {
  C[idx] = v;
}

// ---------------------------------------------------------------------------
// gemm_dp: C[m][n] = sum_k A[m][k]*Bt[n][k] + bias[n].  A,Bt bf16.
// BM=256 x BN=128, BK=64, ring-3 LDS, one gate per K-tile.
// NTB = N/128 (compile-time). Grid: (M/256)*NTB blocks of 512 threads.
// ---------------------------------------------------------------------------
template <typename CT, int NTB>
__global__ __launch_bounds__(512) void gemm_dp(
    const unsigned short* __restrict__ A,
    const unsigned short* __restrict__ Bt,
    const float* __restrict__ bias,
    CT* __restrict__ C,
    int K, int lda, int ldb, int ldc)
{
  __shared__ __align__(16) unsigned short sA[3][256 * 64];  // 96 KB
  __shared__ __align__(16) unsigned short sB[3][128 * 64];  // 48 KB

  const int tid = threadIdx.x;
  const int w   = tid >> 6;   // wave 0..7
  const int l   = tid & 63;
  const int l15 = l & 15;
  const int q   = l >> 4;     // quad 0..3

  // XCD-aware remap: dispatch -> (m,n) so one XCD owns all n-tiles of an m-row
  const int bt  = blockIdx.x;
  const int xcd = bt & 7;
  const int j_  = bt >> 3;
  const int n0  = (j_ % NTB) * 128;
  const int m0  = ((j_ / NTB) * 8 + xcd) * 256;

  const int wm  = (w >> 1) * 64;   // wave row base: 0/64/128/192
  const int wn  = (w & 1) * 64;    // wave col base: 0/64

  floatx4 acc[4][4];
  #pragma unroll
  for (int i = 0; i < 4; ++i)
    #pragma unroll
    for (int j = 0; j < 4; ++j)
      #pragma unroll
      for (int t = 0; t < 4; ++t) acc[i][j][t] = 0.f;

  // ---- staging geometry: each async16 covers 8 rows x 8 chunks (1 KB).
  // Wave w: A rows [w*32, w*32+32) via 4 issues; B rows [w*16, w*16+16) via 2.
  // LDS dest linear (lane l -> row l>>3, phys chunk l&7); global source
  // pre-inverse-swizzled: logical chunk = (l&7) ^ (l>>3)  [= phys ^ (row&7)].
  const int srow8 = l >> 3;                 // row within 8-row group
  const int lc    = ((l & 7) ^ srow8) * 8;  // logical chunk offset (shorts)
  const unsigned short* Asrc = A  + (size_t)(m0 + w * 32 + srow8) * lda + lc;
  const unsigned short* Bsrc = Bt + (size_t)(n0 + w * 16 + srow8) * ldb + lc;

  #define STAGE(k2, b)                                                        \
    {                                                                         \
      _Pragma("unroll")                                                       \
      for (int j = 0; j < 4; ++j)                                             \
        async16(Asrc + (size_t)(j * 8) * lda + (k2),                          \
                &sA[b][(w * 32 + j * 8) * 64]);                               \
      _Pragma("unroll")                                                       \
      for (int j = 0; j < 2; ++j)                                             \
        async16(Bsrc + (size_t)(j * 8) * ldb + (k2),                          \
                &sB[b][(w * 16 + j * 8) * 64]);                               \
    }

  // ---- fragment read addressing: row stride 64 shorts (128 B = 8 chunks).
  // Frag (row, kk, q) at phys chunk (kk*4+q) ^ (row&7); row&7 == l15&7.
  const int rx   = l15 & 7;
  const int pc0  = (q ^ rx) * 8;          // kk=0 chunk offset (shorts)
  const int arow = (wm + l15) * 64;
  const int brow = (wn + l15) * 64;

  const int KT = K >> 6;   // K-tiles of 64

  // ---- prologue: stage tiles 0 and 1 (12 loads/thread in flight)
  STAGE(0, 0);
  STAGE(64, 1);

  int bc = 0;
  for (int t = 0; t < KT; ++t) {
    // gate: drain tile t's 6 loads (issued 2 bodies ago), keep t+1's 6 in
    // flight. Fused wait+barrier so nothing can be scheduled between.
    if (t + 1 < KT)
      asm volatile("s_waitcnt vmcnt(6)\n\ts_barrier" ::: "memory");
    else
      asm volatile("s_waitcnt vmcnt(0)\n\ts_barrier" ::: "memory");

    const int k2 = (t + 2) << 6;
    const int b2 = (bc == 0) ? 2 : bc - 1;   // (bc+2)%3 == (bc-1)%3
    if (k2 < K) STAGE(k2, b2);               // region freed by this gate

    short8 af[2][4], bf[2][4];
    #pragma unroll
    for (int kk = 0; kk < 2; ++kk) {
      const int pcs = pc0 ^ (kk << 5);       // (kk*4+q)^rx chunk, in shorts
      #pragma unroll
      for (int mt = 0; mt < 4; ++mt)
        af[kk][mt] = *(const short8*)(&sA[bc][arow + mt * 1024 + pcs]);
      #pragma unroll
      for (int nt = 0; nt < 4; ++nt)
        bf[kk][nt] = *(const short8*)(&sB[bc][brow + nt * 1024 + pcs]);
    }
    __builtin_amdgcn_s_setprio(1);
    #pragma unroll
    for (int kk = 0; kk < 2; ++kk)
      #pragma unroll
      for (int mt = 0; mt < 4; ++mt)
        #pragma unroll
        for (int nt = 0; nt < 4; ++nt)
          acc[mt][nt] = __builtin_amdgcn_mfma_f32_16x16x32_bf16(
              af[kk][mt], bf[kk][nt], acc[mt][nt], 0, 0, 0);
    __builtin_amdgcn_s_setprio(0);

    bc = (bc == 2) ? 0 : bc + 1;
  }
  #undef STAGE

  // ---- epilogue: C/D layout col=lane&15, row=quad*4+reg
  #pragma unroll
  for (int nt = 0; nt < 4; ++nt) {
    const int col = n0 + wn + nt * 16 + l15;
    const float bs = bias[col];
    #pragma unroll
    for (int mt = 0; mt < 4; ++mt) {
      const int rbase = m0 + wm + mt * 16 + q * 4;
      #pragma unroll
      for (int r = 0; r < 4; ++r)
        storeC(C, (size_t)(rbase + r) * ldc + col, acc[mt][nt][r] + bs);
    }
  }
}

// 4 queries per wave, 16 lanes per query (lane p owns dims p*16..p*16+15).
// QKV row: [Q(0..255) | K(256..511) | V(512..767)], bf16. ctx overwrites Q
// slot in place (each group reads only its own Q row, before its store).
__global__ __launch_bounds__(256) void attn_win(unsigned short* QKV)
{
  const int l   = threadIdx.x & 63;
  const int grp = l >> 4;
  const int p   = l & 15;
  const int i   = blockIdx.x * 16 + (threadIdx.x >> 6) * 4 + grp;

  unsigned short* qrow = QKV + (size_t)i * 768 + p * 16;
  float qf[16];
  {
    const short8 v0 = *(const short8*)(qrow);
    const short8 v1 = *(const short8*)(qrow + 8);
    #pragma unroll
    for (int t = 0; t < 8; ++t) {
      qf[t]     = b2f((unsigned short)v0[t]);
      qf[8 + t] = b2f((unsigned short)v1[t]);
    }
  }

  float sc[9];
  #pragma unroll
  for (int wd = 0; wd < 9; ++wd) {
    const int j = i - 8 + wd;
    if (j >= 0) {
      const unsigned short* krow = QKV + (size_t)j * 768 + 256 + p * 16;
      const short8 v0 = *(const short8*)(krow);
      const short8 v1 = *(const short8*)(krow + 8);
      float d = 0.f;
      #pragma unroll
      for (int t = 0; t < 8; ++t) {
        d += qf[t]     * b2f((unsigned short)v0[t]);
        d += qf[8 + t] * b2f((unsigned short)v1[t]);
      }
      d += __shfl_xor(d, 8, 64);
      d += __shfl_xor(d, 4, 64);
      d += __shfl_xor(d, 2, 64);
      d += __shfl_xor(d, 1, 64);
      sc[wd] = d * 0.0625f;  // 1/sqrt(256)
    } else {
      sc[wd] = -1e30f;  // finite sentinel
    }
  }

  float mx = sc[0];
  #pragma unroll
  for (int wd = 1; wd < 9; ++wd) mx = fmaxf(mx, sc[wd]);
  float e[9], s = 0.f;
  #pragma unroll
  for (int wd = 0; wd < 9; ++wd) { e[wd] = __expf(sc[wd] - mx); s += e[wd]; }
  const float inv = 1.0f / s;

  float acc[16];
  #pragma unroll
  for (int t = 0; t < 16; ++t) acc[t] = 0.f;
  #pragma unroll
  for (int wd = 0; wd < 9; ++wd) {
    const int j = i - 8 + wd;
    if (j >= 0) {
      const unsigned short* vrow = QKV + (size_t)j * 768 + 512 + p * 16;
      const short8 v0 = *(const short8*)(vrow);
      const short8 v1 = *(const short8*)(vrow + 8);
      #pragma unroll
      for (int t = 0; t < 8; ++t) {
        acc[t]     += e[wd] * b2f((unsigned short)v0[t]);
        acc[8 + t] += e[wd] * b2f((unsigned short)v1[t]);
      }
    }
  }
  short8 o0, o1;
  #pragma unroll
  for (int t = 0; t < 8; ++t) {
    o0[t] = (short)f2b(acc[t] * inv);
    o1[t] = (short)f2b(acc[8 + t] * inv);
  }
  *(short8*)(qrow)     = o0;
  *(short8*)(qrow + 8) = o1;
}

// Merged prep: blocks 0..767: Wq/Wk/Wv -> Wt[768][1024] (32x32 LDS transpose
// tiles, f32->bf16); 768..1023: Wo -> Wot[1024][256]; 1024: bias concat;
// 1025..3072: x f32 -> bf16 (2048 grid-stride slices). Weight prep overlaps
// the BW-bound convert instead of serializing before it.
__global__ __launch_bounds__(256) void prep_all(
    const float* __restrict__ Wq, const float* __restrict__ Wk,
    const float* __restrict__ Wv, const float* __restrict__ Wo,
    const float* __restrict__ bq, const float* __restrict__ bk,
    const float* __restrict__ bv, const float* __restrict__ bo,
    const float* __restrict__ x,
    unsigned short* __restrict__ Wt,   // [768][1024] bf16
    unsigned short* __restrict__ Wot,  // [1024][256] bf16
    float* __restrict__ bias1,         // [768] f32
    float* __restrict__ bias2,         // [1024] f32
    unsigned short* __restrict__ xb)   // [32768][1024] bf16
{
  const int bb = blockIdx.x;
  if (bb < 1024) {
    __shared__ float tile[32][33];
    const float* src; unsigned short* dst; int N, Kd, k0, n0;
    if (bb < 768) {
      const int s = bb >> 8;          // 0:Wq 1:Wk 2:Wv
      const int r = bb & 255;
      src = (s == 0) ? Wq : (s == 1) ? Wk : Wv;
      N = 256; Kd = 1024;
      k0 = (r & 31) * 32;
      n0 = (r >> 5) * 32;
      dst = Wt + (size_t)s * 256 * 1024;
    } else {
      const int r = bb - 768;
      src = Wo; N = 1024; Kd = 256;
      k0 = (r & 7) * 32;
      n0 = (r >> 3) * 32;
      dst = Wot;
    }
    const int t  = threadIdx.x;
    const int rr = t >> 3;
    const int c4 = (t & 7) * 4;
    const float4 v = *(const float4*)(src + (size_t)(k0 + rr) * N + n0 + c4);
    tile[rr][c4 + 0] = v.x; tile[rr][c4 + 1] = v.y;
    tile[rr][c4 + 2] = v.z; tile[rr][c4 + 3] = v.w;
    __syncthreads();
    ushort4 o;
    o.x = f2b(tile[c4 + 0][rr]); o.y = f2b(tile[c4 + 1][rr]);
    o.z = f2b(tile[c4 + 2][rr]); o.w = f2b(tile[c4 + 3][rr]);
    *(ushort4*)(dst + (size_t)(n0 + rr) * Kd + k0 + c4) = o;
  } else if (bb == 1024) {
    for (int c = threadIdx.x; c < 1792; c += 256) {
      if (c < 768)
        bias1[c] = (c < 256) ? bq[c] : (c < 512) ? bk[c - 256] : bv[c - 512];
      else
        bias2[c - 768] = bo[c - 768];
    }
  } else {
    // x convert: 4194304 16B-stores over 2048 blocks x 256 threads (8 iters)
    const int n8 = 32768 * 1024 / 8;
    const int stride = 2048 * 256;
    for (int i = (bb - 1025) * 256 + threadIdx.x; i < n8; i += stride) {
      const float4 u = ((const float4*)x)[2 * i];
      const float4 v = ((const float4*)x)[2 * i + 1];
      uint4 pk;
      pk.x = pack2bf(u.x, u.y); pk.y = pack2bf(u.z, u.w);
      pk.z = pack2bf(v.x, v.y); pk.w = pack2bf(v.z, v.w);
      ((uint4*)xb)[i] = pk;
    }
  }
}

extern "C" void kernel_launch(void* const* d_in, const int* in_sizes, int n_in,
                              void* d_out, int out_size, void* d_ws, size_t ws_size,
                              hipStream_t stream) {
  const float* x  = (const float*)d_in[0];
  const float* Wq = (const float*)d_in[1];
  const float* Wk = (const float*)d_in[2];
  const float* Wv = (const float*)d_in[3];
  const float* Wo = (const float*)d_in[4];
  const float* bq = (const float*)d_in[5];
  const float* bk = (const float*)d_in[6];
  const float* bv = (const float*)d_in[7];
  const float* bo = (const float*)d_in[8];
  float* out = (float*)d_out;

  // workspace layout — xb spills into d_out if ws is small
  // (d_out = 134 MB, only consumed by the last GEMM => stream-ordered safe).
  unsigned short* ws    = (unsigned short*)d_ws;
  unsigned short* Wt    = ws;                        //   786432 bf16
  unsigned short* Wot   = Wt  + 786432;              //   262144 bf16
  float*          bias1 = (float*)(Wot + 262144);    //      768 f32
  float*          bias2 = bias1 + 768;               //     1024 f32
  unsigned short* QKV   = (unsigned short*)(bias2 + 1024);  // 25165824 bf16
  unsigned short* xb;                                // 33554432 bf16
  const size_t need = 119544832;                     // bytes incl. xb
  if (ws_size >= need) xb = QKV + 25165824;
  else                 xb = (unsigned short*)d_out;  // scratch until last GEMM

  // weight transposes + bias concat + x convert (overlapped in one grid)
  prep_all<<<3073, 256, 0, stream>>>(Wq, Wk, Wv, Wo, bq, bk, bv, bo, x,
                                     Wt, Wot, bias1, bias2, xb);

  // QKV = x @ [Wq|Wk|Wv] + bias   (M=32768, N=768, K=1024)
  // 128 m-tiles x 6 n-tiles = 768 blocks @1/CU = 3 exact dispatch rounds
  gemm_dp<unsigned short, 6><<<768, 512, 0, stream>>>(
      xb, Wt, bias1, QKV, 1024, 1024, 1024, 768);

  // windowed attention: ctx overwrites the Q slot of QKV
  attn_win<<<2048, 256, 0, stream>>>(QKV);

  // out = ctx @ Wo + bo   (M=32768, N=1024, K=256; A = QKV with lda=768)
  gemm_dp<float, 8><<<1024, 512, 0, stream>>>(
      QKV, Wot, bias2, out, 256, 768, 256, 1024);
}

// Round 5
// 369.406 us; speedup vs baseline: 1.0121x; 1.0121x over previous
//
#include <hip/hip_runtime.h>
#include <stdint.h>

// ---------------------------------------------------------------------------
// OptitationLayer: sliding-window attention (W=9) with projections.
//   S=32768, D=1024, R=256. Inputs/outputs FLOAT32; bf16 MFMA internally.
// Pipeline (4 kernels):
//   prep_all: weight transposes f32->bf16 (blocks 0..1024) OVERLAPPED with
//             x f32->bf16 convert (blocks 1025..3072)
//   gemm_bt : QKV[S][768] bf16 = x_bf16 @ W + bias   (R1-verified 128^2 tile)
//   attn    : QKV[i][0:256] <- softmax-window ctx (in-place, 4 queries/wave)
//   gemm_bt : out[S][1024] f32 = ctx @ Wo + bo
//
// gemm_bt is the measured-best structure from this session (363.0 us total):
//   128x128 tile, 4 waves, BK=64, single-buffered LDS (32 KB -> 3 blocks/CU
//   = 12 waves/CU), async16 global_load_lds staging, XOR chunk swizzle
//   (0 bank conflicts), 2 __syncthreads per K-tile. Schedule experiments
//   (ring-3 counted vmcnt @3blk/CU: null; 256^2 and 256x128 deep pipelines
//   @1blk/CU: -7%) all failed to beat it -- occupancy/TLP dominates source-
//   level pipelining on this shape (m131-m141 behavior reproduced).
// XCD swizzle: dispatch i -> XCD i%8; all n-tiles of an m-row on ONE xcd
// so the A panel is fetched by a single L2.
// ---------------------------------------------------------------------------

typedef __attribute__((ext_vector_type(8))) short short8;   // 8 x bf16 frag
typedef __attribute__((ext_vector_type(4))) float floatx4;  // MFMA acc

typedef __attribute__((address_space(1))) const void global_cv;
typedef __attribute__((address_space(3))) void lds_v;

__device__ __forceinline__ float b2f(unsigned short u) {
  union { float f; uint32_t i; } v; v.i = ((uint32_t)u) << 16; return v.f;
}
__device__ __forceinline__ unsigned short f2b(float f) {
  union { float f; uint32_t i; } v; v.f = f;
  uint32_t x = v.i;
  return (unsigned short)((x + 0x7FFFu + ((x >> 16) & 1u)) >> 16);
}
// pack two f32 -> two bf16 (round half-up; 3 VALU ops)
__device__ __forceinline__ uint32_t pack2bf(float a, float b) {
  uint32_t ua = (__float_as_uint(a) + 0x8000u) >> 16;
  uint32_t ub = (__float_as_uint(b) + 0x8000u) & 0xFFFF0000u;
  return ua | ub;
}

// async 16B global->LDS; lane i lands at lds_base + i*16 (wave-uniform base)
__device__ __forceinline__ void async16(const unsigned short* g, unsigned short* s) {
  __builtin_amdgcn_global_load_lds((global_cv*)g, (lds_v*)s, 16, 0, 0);
}

__device__ __forceinline__ void storeC(unsigned short* C, size_t idx, float v) {
  C[idx] = f2b(v);
}
__device__ __forceinline__ void storeC(float* C, size_t idx, float v) {
  C[idx] = v;
}

// C[m][n] = sum_k A[m][k]*Bt[n][k] + bias[n].  A bf16 via async staging.
// Grid: 1-D, (M/128)*NT blocks; NT = N/128 (compile-time).
template <typename CT, int NT>
__global__ __launch_bounds__(256) void gemm_bt(
    const unsigned short* __restrict__ A,
    const unsigned short* __restrict__ Bt,   // [N x ldb] bf16
    const float* __restrict__ bias,          // [N] f32
    CT* __restrict__ C,                      // [M x ldc]
    int K, int lda, int ldb, int ldc)
{
  __shared__ __align__(16) unsigned short sA[128 * 64];  // 16 KB
  __shared__ __align__(16) unsigned short sB[128 * 64];  // 16 KB

  const int tid = threadIdx.x;
  const int w   = tid >> 6;   // wave 0..3
  const int l   = tid & 63;   // lane
  const int l15 = l & 15;
  const int q   = l >> 4;     // quad 0..3

  // XCD-aware remap: dispatch -> (m,n) so one XCD owns all n-tiles of an m-row
  const int bt  = blockIdx.x;
  const int xcd = bt & 7;
  const int j_  = bt >> 3;
  const int n0  = (j_ % NT) * 128;
  const int m0  = ((j_ / NT) * 8 + xcd) * 128;

  const int wm  = (w >> 1) * 64;      // wave's 64x64 quadrant
  const int wn  = (w & 1) * 64;

  floatx4 acc[4][4];
  #pragma unroll
  for (int i = 0; i < 4; ++i)
    #pragma unroll
    for (int j = 0; j < 4; ++j)
      #pragma unroll
      for (int t = 0; t < 4; ++t) acc[i][j][t] = 0.f;

  const int srow = l >> 3;  // staging row within 8-row group
  const int sch  = l & 7;   // physical 16B chunk within the row

  for (int k0 = 0; k0 < K; k0 += 64) {
    // ---- B staging: async 16B, XOR-swizzled chunks
    #pragma unroll
    for (int jj = 0; jj < 4; ++jj) {
      const int rr = (jj * 4 + w) * 8 + srow;
      const int kc = sch ^ (rr & 7);
      async16(Bt + (size_t)(n0 + rr) * ldb + (k0 + kc * 8),
              sB + (jj * 4 + w) * 512);
    }
    // ---- A staging
    #pragma unroll
    for (int jj = 0; jj < 4; ++jj) {
      const int rr = (jj * 4 + w) * 8 + srow;
      const int kc = sch ^ (rr & 7);
      async16(A + (size_t)(m0 + rr) * lda + (k0 + kc * 8),
              sA + (jj * 4 + w) * 512);
    }
    __syncthreads();  // drains vmcnt + lgkmcnt -> LDS data visible

    #pragma unroll
    for (int kt = 0; kt < 2; ++kt) {
      short8 af[4], bf[4];
      #pragma unroll
      for (int mt = 0; mt < 4; ++mt) {
        const int row = wm + mt * 16 + l15;
        const int pc  = (kt * 4 + q) ^ (row & 7);
        af[mt] = *(const short8*)(sA + row * 64 + pc * 8);  // ds_read_b128
      }
      #pragma unroll
      for (int nt = 0; nt < 4; ++nt) {
        const int row = wn + nt * 16 + l15;
        const int pc  = (kt * 4 + q) ^ (row & 7);
        bf[nt] = *(const short8*)(sB + row * 64 + pc * 8);
      }
      #pragma unroll
      for (int mt = 0; mt < 4; ++mt)
        #pragma unroll
        for (int nt = 0; nt < 4; ++nt)
          acc[mt][nt] = __builtin_amdgcn_mfma_f32_16x16x32_bf16(
              af[mt], bf[nt], acc[mt][nt], 0, 0, 0);
    }
    __syncthreads();  // protect LDS before next staging pass
  }

  // ---- epilogue: C/D layout col=lane&15, row=quad*4+reg
  #pragma unroll
  for (int nt = 0; nt < 4; ++nt) {
    const int col = n0 + wn + nt * 16 + l15;
    const float bs = bias[col];
    #pragma unroll
    for (int mt = 0; mt < 4; ++mt) {
      const int rbase = m0 + wm + mt * 16 + q * 4;
      #pragma unroll
      for (int r = 0; r < 4; ++r)
        storeC(C, (size_t)(rbase + r) * ldc + col, acc[mt][nt][r] + bs);
    }
  }
}

// 4 queries per wave, 16 lanes per query (lane p owns dims p*16..p*16+15).
// QKV row: [Q(0..255) | K(256..511) | V(512..767)], bf16. ctx overwrites Q
// slot in place (each group reads only its own Q row, before its store).
__global__ __launch_bounds__(256) void attn_win(unsigned short* QKV)
{
  const int l   = threadIdx.x & 63;
  const int grp = l >> 4;
  const int p   = l & 15;
  const int i   = blockIdx.x * 16 + (threadIdx.x >> 6) * 4 + grp;

  unsigned short* qrow = QKV + (size_t)i * 768 + p * 16;
  float qf[16];
  {
    const short8 v0 = *(const short8*)(qrow);
    const short8 v1 = *(const short8*)(qrow + 8);
    #pragma unroll
    for (int t = 0; t < 8; ++t) {
      qf[t]     = b2f((unsigned short)v0[t]);
      qf[8 + t] = b2f((unsigned short)v1[t]);
    }
  }

  float sc[9];
  #pragma unroll
  for (int wd = 0; wd < 9; ++wd) {
    const int j = i - 8 + wd;
    if (j >= 0) {
      const unsigned short* krow = QKV + (size_t)j * 768 + 256 + p * 16;
      const short8 v0 = *(const short8*)(krow);
      const short8 v1 = *(const short8*)(krow + 8);
      float d = 0.f;
      #pragma unroll
      for (int t = 0; t < 8; ++t) {
        d += qf[t]     * b2f((unsigned short)v0[t]);
        d += qf[8 + t] * b2f((unsigned short)v1[t]);
      }
      d += __shfl_xor(d, 8, 64);
      d += __shfl_xor(d, 4, 64);
      d += __shfl_xor(d, 2, 64);
      d += __shfl_xor(d, 1, 64);
      sc[wd] = d * 0.0625f;  // 1/sqrt(256)
    } else {
      sc[wd] = -1e30f;  // finite sentinel
    }
  }

  float mx = sc[0];
  #pragma unroll
  for (int wd = 1; wd < 9; ++wd) mx = fmaxf(mx, sc[wd]);
  float e[9], s = 0.f;
  #pragma unroll
  for (int wd = 0; wd < 9; ++wd) { e[wd] = __expf(sc[wd] - mx); s += e[wd]; }
  const float inv = 1.0f / s;

  float acc[16];
  #pragma unroll
  for (int t = 0; t < 16; ++t) acc[t] = 0.f;
  #pragma unroll
  for (int wd = 0; wd < 9; ++wd) {
    const int j = i - 8 + wd;
    if (j >= 0) {
      const unsigned short* vrow = QKV + (size_t)j * 768 + 512 + p * 16;
      const short8 v0 = *(const short8*)(vrow);
      const short8 v1 = *(const short8*)(vrow + 8);
      #pragma unroll
      for (int t = 0; t < 8; ++t) {
        acc[t]     += e[wd] * b2f((unsigned short)v0[t]);
        acc[8 + t] += e[wd] * b2f((unsigned short)v1[t]);
      }
    }
  }
  short8 o0, o1;
  #pragma unroll
  for (int t = 0; t < 8; ++t) {
    o0[t] = (short)f2b(acc[t] * inv);
    o1[t] = (short)f2b(acc[8 + t] * inv);
  }
  *(short8*)(qrow)     = o0;   // overwrite Q slot
  *(short8*)(qrow + 8) = o1;
}

// Merged prep: blocks 0..767: Wq/Wk/Wv -> Wt[768][1024] (32x32 LDS transpose
// tiles, f32->bf16); 768..1023: Wo -> Wot[1024][256]; 1024: bias concat;
// 1025..3072: x f32 -> bf16 (2048 grid-stride slices). Weight prep overlaps
// the BW-bound convert instead of serializing before it.
__global__ __launch_bounds__(256) void prep_all(
    const float* __restrict__ Wq, const float* __restrict__ Wk,
    const float* __restrict__ Wv, const float* __restrict__ Wo,
    const float* __restrict__ bq, const float* __restrict__ bk,
    const float* __restrict__ bv, const float* __restrict__ bo,
    const float* __restrict__ x,
    unsigned short* __restrict__ Wt,   // [768][1024] bf16
    unsigned short* __restrict__ Wot,  // [1024][256] bf16
    float* __restrict__ bias1,         // [768] f32
    float* __restrict__ bias2,         // [1024] f32
    unsigned short* __restrict__ xb)   // [32768][1024] bf16
{
  const int bb = blockIdx.x;
  if (bb < 1024) {
    __shared__ float tile[32][33];
    const float* src; unsigned short* dst; int N, Kd, k0, n0;
    if (bb < 768) {
      const int s = bb >> 8;          // 0:Wq 1:Wk 2:Wv
      const int r = bb & 255;
      src = (s == 0) ? Wq : (s == 1) ? Wk : Wv;
      N = 256; Kd = 1024;
      k0 = (r & 31) * 32;             // 32 k-tiles
      n0 = (r >> 5) * 32;             // 8 n-tiles
      dst = Wt + (size_t)s * 256 * 1024;
    } else {
      const int r = bb - 768;
      src = Wo; N = 1024; Kd = 256;
      k0 = (r & 7) * 32;              // 8 k-tiles
      n0 = (r >> 3) * 32;             // 32 n-tiles
      dst = Wot;
    }
    const int t  = threadIdx.x;
    const int rr = t >> 3;            // 0..31
    const int c4 = (t & 7) * 4;       // 0,4,..,28
    const float4 v = *(const float4*)(src + (size_t)(k0 + rr) * N + n0 + c4);
    tile[rr][c4 + 0] = v.x; tile[rr][c4 + 1] = v.y;
    tile[rr][c4 + 2] = v.z; tile[rr][c4 + 3] = v.w;
    __syncthreads();
    ushort4 o;
    o.x = f2b(tile[c4 + 0][rr]); o.y = f2b(tile[c4 + 1][rr]);
    o.z = f2b(tile[c4 + 2][rr]); o.w = f2b(tile[c4 + 3][rr]);
    *(ushort4*)(dst + (size_t)(n0 + rr) * Kd + k0 + c4) = o;
  } else if (bb == 1024) {
    for (int c = threadIdx.x; c < 1792; c += 256) {
      if (c < 768)
        bias1[c] = (c < 256) ? bq[c] : (c < 512) ? bk[c - 256] : bv[c - 512];
      else
        bias2[c - 768] = bo[c - 768];
    }
  } else {
    // x convert: 4194304 16B-stores over 2048 blocks x 256 threads (8 iters)
    const int n8 = 32768 * 1024 / 8;
    const int stride = 2048 * 256;
    for (int i = (bb - 1025) * 256 + threadIdx.x; i < n8; i += stride) {
      const float4 u = ((const float4*)x)[2 * i];
      const float4 v = ((const float4*)x)[2 * i + 1];
      uint4 pk;
      pk.x = pack2bf(u.x, u.y); pk.y = pack2bf(u.z, u.w);
      pk.z = pack2bf(v.x, v.y); pk.w = pack2bf(v.z, v.w);
      ((uint4*)xb)[i] = pk;
    }
  }
}

extern "C" void kernel_launch(void* const* d_in, const int* in_sizes, int n_in,
                              void* d_out, int out_size, void* d_ws, size_t ws_size,
                              hipStream_t stream) {
  const float* x  = (const float*)d_in[0];
  const float* Wq = (const float*)d_in[1];
  const float* Wk = (const float*)d_in[2];
  const float* Wv = (const float*)d_in[3];
  const float* Wo = (const float*)d_in[4];
  const float* bq = (const float*)d_in[5];
  const float* bk = (const float*)d_in[6];
  const float* bv = (const float*)d_in[7];
  const float* bo = (const float*)d_in[8];
  float* out = (float*)d_out;

  // workspace layout — xb spills into d_out if ws is small
  // (d_out = 134 MB, only consumed by the last GEMM => stream-ordered safe).
  unsigned short* ws    = (unsigned short*)d_ws;
  unsigned short* Wt    = ws;                        //   786432 bf16
  unsigned short* Wot   = Wt  + 786432;              //   262144 bf16
  float*          bias1 = (float*)(Wot + 262144);    //      768 f32
  float*          bias2 = bias1 + 768;               //     1024 f32
  unsigned short* QKV   = (unsigned short*)(bias2 + 1024);  // 25165824 bf16
  unsigned short* xb;                                // 33554432 bf16
  const size_t need = 119544832;                     // bytes incl. xb
  if (ws_size >= need) xb = QKV + 25165824;
  else                 xb = (unsigned short*)d_out;  // scratch until last GEMM

  // weight transposes + bias concat + x convert (overlapped in one grid)
  prep_all<<<3073, 256, 0, stream>>>(Wq, Wk, Wv, Wo, bq, bk, bv, bo, x,
                                     Wt, Wot, bias1, bias2, xb);

  // QKV = x @ [Wq|Wk|Wv] + bias   (M=32768, N=768, K=1024)
  gemm_bt<unsigned short, 6><<<1536, 256, 0, stream>>>(
      xb, Wt, bias1, QKV, 1024, 1024, 1024, 768);

  // windowed attention: ctx overwrites the Q slot of QKV
  attn_win<<<2048, 256, 0, stream>>>(QKV);

  // out = ctx @ Wo + bo   (M=32768, N=1024, K=256; A = QKV with lda=768)
  gemm_bt<float, 8><<<2048, 256, 0, stream>>>(
      QKV, Wot, bias2, out, 256, 768, 256, 1024);
}